// Round 6
// baseline (368.231 us; speedup 1.0000x reference)
//
#include <hip/hip_runtime.h>
#include <math.h>

// Problem constants (fixed by the reference)
#define BB 128          // batch
#define CC 100000       // classes
#define FF 256          // feature dim
#define NB 64           // classes per workgroup (4 waves x 16 cols)
#define NWG ((CC + NB - 1) / NB)   // 1563
#define SCALARF 20.0f

typedef __attribute__((ext_vector_type(8))) short short8;   // 8 bf16 = 4 VGPR (MFMA A/B frag)
typedef __attribute__((ext_vector_type(4))) float f32x4;    // MFMA C/D frag

// ---- fp32 -> bf16 split helpers (RNE via bit trick; deterministic) ----
__device__ __forceinline__ unsigned short bf16_rne(float f) {
    unsigned int u = __float_as_uint(f);
    u += 0x7FFFu + ((u >> 16) & 1u);
    return (unsigned short)(u >> 16);
}
__device__ __forceinline__ float bf16_to_f32(unsigned short h) {
    return __uint_as_float((unsigned int)h << 16);
}
__device__ __forceinline__ void split8(const float4& a, const float4& b,
                                       short8& hi, short8& lo) {
    float v[8] = {a.x, a.y, a.z, a.w, b.x, b.y, b.z, b.w};
#pragma unroll
    for (int j = 0; j < 8; ++j) {
        unsigned short h = bf16_rne(v[j]);
        hi[j] = (short)h;
        lo[j] = (short)bf16_rne(v[j] - bf16_to_f32(h));
    }
}

// ---------------------------------------------------------------------------
// K0: pre-split scaled inputs (x20) into MFMA A-fragment layout, hi/lo bf16.
// wsA[((kc*8+mt)*2+h)*512 + lane*8 + j]
//   = bf16_part_h( 20 * inputs[(lane&15)+16*mt][kc*32 + (lane>>4)*8 + j] )
// Same positional k-map as the B-frag ds_reads in K1 -> HW k-permutation cancels.
// ---------------------------------------------------------------------------
__global__ __launch_bounds__(256) void k_prep(const float* __restrict__ inputs,
                                              unsigned short* __restrict__ wsA)
{
    int t    = blockIdx.x * 256 + threadIdx.x;   // 0..4095
    int lane = t & 63;
    int mt   = (t >> 6) & 7;
    int kc   = t >> 9;
    int row  = (lane & 15) + 16 * mt;
    int k0   = kc * 32 + ((lane >> 4) << 3);
    const float* src = inputs + (size_t)row * FF + k0;
    float4 x0 = *(const float4*)(src);
    float4 x1 = *(const float4*)(src + 4);
    float v[8] = {x0.x, x0.y, x0.z, x0.w, x1.x, x1.y, x1.z, x1.w};
    unsigned short h[8], l[8];
#pragma unroll
    for (int j = 0; j < 8; ++j) {
        float a = v[j] * SCALARF;
        h[j] = bf16_rne(a);
        l[j] = bf16_rne(a - bf16_to_f32(h[j]));
    }
    size_t base = (size_t)(kc * 8 + mt) * 2 * 512;   // frag = 512 ushorts = 1KB
    uint4 ph, pl;
    ph.x = (unsigned)h[0] | ((unsigned)h[1] << 16);
    ph.y = (unsigned)h[2] | ((unsigned)h[3] << 16);
    ph.z = (unsigned)h[4] | ((unsigned)h[5] << 16);
    ph.w = (unsigned)h[6] | ((unsigned)h[7] << 16);
    pl.x = (unsigned)l[0] | ((unsigned)l[1] << 16);
    pl.y = (unsigned)l[2] | ((unsigned)l[3] << 16);
    pl.z = (unsigned)l[4] | ((unsigned)l[5] << 16);
    pl.w = (unsigned)l[6] | ((unsigned)l[7] << 16);
    *(uint4*)(wsA + base + lane * 8)       = ph;
    *(uint4*)(wsA + base + 512 + lane * 8) = pl;
}

// ---------------------------------------------------------------------------
// Stage one K-chunk of B (both LUTs, 64 cols x 32 floats = 16KB) into LDS via
// async global_load_lds. LDS dest is LINEAR (slot s = lut*512+col*8+t, 16B
// units); the XOR swizzle ((t*16)^((col&7)<<4)) is applied to the GLOBAL
// source offset (rule #21: linear dest + inverse-swizzled source + swizzled
// read = consistent involution). vmcnt-only; consumed later via ds_read.
// ---------------------------------------------------------------------------
__device__ __forceinline__ void stage_chunk(
    const float* __restrict__ lutc, const float* __restrict__ luti,
    float* buf, int w, int lane, int cbase, int kc)
{
    const int dc = lane >> 3;      // col-within-group 0..7
    const int t  = lane & 7;       // 16B unit within 128B col-chunk
#pragma unroll
    for (int r = 0; r < 4; ++r) {
        const int s0   = 256 * r + 64 * w;       // wave-uniform slot base
        const int lut  = s0 >> 9;                // 0,0,1,1 across r
        const int c0   = (s0 >> 3) & 63;
        const int colb = c0 + dc;
        int srow = cbase + colb;
        srow = (srow < CC) ? srow : (CC - 1);    // clamp tail (masked later)
        const float* lp = lut ? luti : lutc;
        const char* src = (const char*)lp + (size_t)srow * 1024 + kc * 128
                          + ((t * 16) ^ ((colb & 7) << 4));
        char* dst = (char*)buf + s0 * 16;        // wave-uniform; +lane*16 implicit
        __builtin_amdgcn_global_load_lds(
            (const __attribute__((address_space(1))) unsigned int*)src,
            (__attribute__((address_space(3))) unsigned int*)dst,
            16, 0, 0);
    }
}

// ---------------------------------------------------------------------------
// K1: dual-GEMM via bf16-split MFMA (Ah*Bh + Al*Bh + Ah*Bl).
// B double-buffered through LDS (lgkmcnt consume; vmcnt DMA drains at the
// pre-barrier waitcnt, ~1500cy after issue = free). A-frags are plain global
// loads issued FIRST each iteration, so the compiler's counted vmcnt wait for
// them never drains the B-DMA stream. One barrier per iteration.
// ---------------------------------------------------------------------------
__global__ __launch_bounds__(256, 2) void k_main_mfma(
    const unsigned short* __restrict__ wsA,
    const float* __restrict__ lutc,
    const float* __restrict__ luti,
    float* __restrict__ maxp,           // [2][128][NWG]
    float* __restrict__ sep,            // [2][128][NWG]
    float* __restrict__ slp,            // [2][128][NWG]
    float* __restrict__ hubp)           // [NWG]
{
    __shared__ float smem[8192];        // 32KB: 2 x 16KB B buffers; epilogue aliases

    const int tid  = threadIdx.x;
    const int w    = tid >> 6;        // wave 0..3
    const int lane = tid & 63;
    const int cg   = lane & 15;       // col within wave's 16
    const int g    = lane >> 4;       // k-subgroup / D-row group
    const int wg   = blockIdx.x;
    const int cbase = wg * NB;
    const int colB = w * 16 + cg;     // col within block 0..63
    const int col  = cbase + colB;
    const bool valid = col < CC;
    const int sw   = (colB & 7) << 4; // read-side swizzle (matches source swizzle)

    f32x4 acc[2][8];
#pragma unroll
    for (int l2 = 0; l2 < 2; ++l2)
#pragma unroll
        for (int mt = 0; mt < 8; ++mt) acc[l2][mt] = (f32x4)(0.0f);

    // ---- prologue: stage chunk 0 into buf0 (barrier drains the DMA) ----
    stage_chunk(lutc, luti, smem, w, lane, cbase, 0);
    __syncthreads();

#pragma unroll
    for (int kc = 0; kc < 8; ++kc) {
        float* bufC = smem + (kc & 1) * 4096;          // compute buffer
        float* bufN = smem + ((kc + 1) & 1) * 4096;    // DMA target

        // 1. A-frags for this chunk — issued FIRST (oldest in vmcnt stream,
        //    so waiting on them leaves the later B-DMA in flight).
        short8 aF0[8], aF1[8];
#pragma unroll
        for (int mt = 0; mt < 8; ++mt) {
            const unsigned short* ab = wsA + (size_t)(kc * 8 + mt) * 1024 + lane * 8;
            aF0[mt] = *(const short8*)(ab);
            aF1[mt] = *(const short8*)(ab + 512);
        }
        // 2. async-stage next chunk's B into the other buffer
        if (kc < 7) stage_chunk(lutc, luti, bufN, w, lane, cbase, kc + 1);

        // 3. read this chunk's B from LDS (lgkmcnt — independent of vmcnt)
        const char* bc = (const char*)bufC + colB * 128;
        float4 c0v = *(const float4*)(bc + ((g * 32) ^ sw));
        float4 c1v = *(const float4*)(bc + ((g * 32 + 16) ^ sw));
        float4 i0v = *(const float4*)(bc + 8192 + ((g * 32) ^ sw));
        float4 i1v = *(const float4*)(bc + 8192 + ((g * 32 + 16) ^ sw));
        short8 bhC, blC, bhI, blI;
        split8(c0v, c1v, bhC, blC);
        split8(i0v, i1v, bhI, blI);

        // 4. 48 MFMAs (compiler waits counted vmcnt for aF; B-DMA stays live)
#pragma unroll
        for (int mt = 0; mt < 8; ++mt) {
            acc[0][mt] = __builtin_amdgcn_mfma_f32_16x16x32_bf16(aF0[mt], bhC, acc[0][mt], 0, 0, 0);
            acc[0][mt] = __builtin_amdgcn_mfma_f32_16x16x32_bf16(aF1[mt], bhC, acc[0][mt], 0, 0, 0);
            acc[0][mt] = __builtin_amdgcn_mfma_f32_16x16x32_bf16(aF0[mt], blC, acc[0][mt], 0, 0, 0);
            acc[1][mt] = __builtin_amdgcn_mfma_f32_16x16x32_bf16(aF0[mt], bhI, acc[1][mt], 0, 0, 0);
            acc[1][mt] = __builtin_amdgcn_mfma_f32_16x16x32_bf16(aF1[mt], bhI, acc[1][mt], 0, 0, 0);
            acc[1][mt] = __builtin_amdgcn_mfma_f32_16x16x32_bf16(aF0[mt], blI, acc[1][mt], 0, 0, 0);
        }
        // 5. barrier: implicit vmcnt(0) drain retires the B-DMA (covered by
        //    the co-resident block's waves); also guards buffer reuse.
        __syncthreads();
    }

    // ---- epilogue (LDS B-buffers are dead; alias reduction arrays) ----
    float* sMax = smem;            // [2][4][128]
    float* sSe  = smem + 1024;
    float* sSl  = smem + 2048;
    float* hsh  = smem + 3072;     // [4]

    // D layout (m89-verified): col = lane&15 (class), row = 16*mt + 4*g + j (sample)

    // smooth-L1 partial (valid cols only)
    float hloc = 0.f;
#pragma unroll
    for (int mt = 0; mt < 8; ++mt)
#pragma unroll
        for (int j = 0; j < 4; ++j) {
            float d = fabsf(acc[0][mt][j] - acc[1][mt][j]);
            float hv = (d < 1.f) ? 0.5f * d * d : d - 0.5f;
            hloc += valid ? hv : 0.f;
        }

    // per-sample-row softmax partials over this wave's 16 cols
#pragma unroll
    for (int l2 = 0; l2 < 2; ++l2) {
#pragma unroll
        for (int mt = 0; mt < 8; ++mt) {
#pragma unroll
            for (int j = 0; j < 4; ++j) {
                float v  = acc[l2][mt][j];
                float mv = valid ? v : -3.0e38f;
                mv = fmaxf(mv, __shfl_xor(mv, 1));
                mv = fmaxf(mv, __shfl_xor(mv, 2));
                mv = fmaxf(mv, __shfl_xor(mv, 4));
                mv = fmaxf(mv, __shfl_xor(mv, 8));
                float e  = valid ? __expf(v - mv) : 0.f;
                float sl = valid ? v : 0.f;
                e  += __shfl_xor(e, 1);  e  += __shfl_xor(e, 2);
                e  += __shfl_xor(e, 4);  e  += __shfl_xor(e, 8);
                sl += __shfl_xor(sl, 1); sl += __shfl_xor(sl, 2);
                sl += __shfl_xor(sl, 4); sl += __shfl_xor(sl, 8);
                if (cg == 0) {
                    int r = 16 * mt + 4 * g + j;
                    sMax[(l2 * 4 + w) * 128 + r] = mv;
                    sSe [(l2 * 4 + w) * 128 + r] = e;
                    sSl [(l2 * 4 + w) * 128 + r] = sl;
                }
            }
        }
    }

    // huber wave reduce -> block
#pragma unroll
    for (int off = 1; off < 64; off <<= 1) hloc += __shfl_xor(hloc, off);
    if (lane == 0) hsh[w] = hloc;
    __syncthreads();

    // combine 4 waves per (lut,row) and write global partials
    {
        int l2 = tid >> 7, r = tid & 127;
        float m0 = sMax[(l2 * 4 + 0) * 128 + r], m1 = sMax[(l2 * 4 + 1) * 128 + r];
        float m2 = sMax[(l2 * 4 + 2) * 128 + r], m3 = sMax[(l2 * 4 + 3) * 128 + r];
        float m  = fmaxf(fmaxf(m0, m1), fmaxf(m2, m3));
        float se = sSe[(l2 * 4 + 0) * 128 + r] * __expf(m0 - m)
                 + sSe[(l2 * 4 + 1) * 128 + r] * __expf(m1 - m)
                 + sSe[(l2 * 4 + 2) * 128 + r] * __expf(m2 - m)
                 + sSe[(l2 * 4 + 3) * 128 + r] * __expf(m3 - m);
        float sl = sSl[(l2 * 4 + 0) * 128 + r] + sSl[(l2 * 4 + 1) * 128 + r]
                 + sSl[(l2 * 4 + 2) * 128 + r] + sSl[(l2 * 4 + 3) * 128 + r];
        size_t o = ((size_t)(l2 * BB + r)) * NWG + wg;
        maxp[o] = m; sep[o] = se; slp[o] = sl;
    }
    if (tid == 0) hubp[wg] = hsh[0] + hsh[1] + hsh[2] + hsh[3];
}

// ---------------------------------------------------------------------------
// K2: combine split-softmax partials per (lut, sample); target logit dot.
// Grid: 256 blocks (lut*128+b) x 256 threads.
// ---------------------------------------------------------------------------
__global__ __launch_bounds__(256) void k_reduce(
    const float* __restrict__ inputs, const int* __restrict__ targets,
    const float* __restrict__ lutc, const float* __restrict__ luti,
    const float* __restrict__ maxp, const float* __restrict__ sep,
    const float* __restrict__ slp, float* __restrict__ vvals)
{
    __shared__ float sM[4], sS[4], sSL[4], sDP;
    const int l    = blockIdx.x >> 7;
    const int b    = blockIdx.x & 127;
    const int tid  = threadIdx.x;
    const int wv   = tid >> 6;
    const int lane = tid & 63;
    const size_t base = ((size_t)(l * BB + b)) * NWG;

    float M = -3.0e38f, S = 0.f, SL = 0.f;
    for (int w = tid; w < NWG; w += 256) {
        float m = maxp[base + w];
        float s = sep[base + w];
        float nM = fmaxf(M, m);
        S = S * __expf(M - nM) + s * __expf(m - nM);
        M = nM;
        SL += slp[base + w];
    }
#pragma unroll
    for (int off = 1; off < 64; off <<= 1) {
        float m2 = __shfl_xor(M, off), s2 = __shfl_xor(S, off), sl2 = __shfl_xor(SL, off);
        float nM = fmaxf(M, m2);
        S = S * __expf(M - nM) + s2 * __expf(m2 - nM);
        M = nM;
        SL += sl2;
    }
    // target logit: wave 0 does the 256-feature fp32 dot
    if (wv == 0) {
        const int tgt = targets[b];
        const float* lut = (l == 0 ? lutc : luti) + (size_t)tgt * FF;
        const float* inp = inputs + (size_t)b * FF;
        float4 x = *(const float4*)(inp + lane * 4);
        float4 y = *(const float4*)(lut + lane * 4);
        float dp = x.x * y.x + x.y * y.y + x.z * y.z + x.w * y.w;
#pragma unroll
        for (int off = 1; off < 64; off <<= 1) dp += __shfl_xor(dp, off);
        if (lane == 0) sDP = dp;
    }
    if (lane == 0) { sM[wv] = M; sS[wv] = S; sSL[wv] = SL; }
    __syncthreads();
    if (tid == 0) {
        float m = fmaxf(fmaxf(sM[0], sM[1]), fmaxf(sM[2], sM[3]));
        float S4 = 0.f, SL4 = 0.f;
#pragma unroll
        for (int i = 0; i < 4; ++i) {
            S4  += sS[i] * __expf(sM[i] - m);
            SL4 += sSL[i];
        }
        float lt  = SCALARF * sDP;
        float lse = m + __logf(S4);
        vvals[blockIdx.x] = 0.9f * (lse - lt) + 0.1f * (lse - SL4 / (float)CC);
    }
}

// ---------------------------------------------------------------------------
// K3: final scalar reduction.
// ---------------------------------------------------------------------------
__global__ __launch_bounds__(256) void k_final(
    const float* __restrict__ vvals, const float* __restrict__ hubp,
    float* __restrict__ out)
{
    __shared__ float sv[4], sh2[4];
    const int tid = threadIdx.x;
    float v = vvals[tid];            // exactly 256 values
    float h = 0.f;
    for (int w = tid; w < NWG; w += 256) h += hubp[w];
#pragma unroll
    for (int off = 1; off < 64; off <<= 1) {
        v += __shfl_xor(v, off);
        h += __shfl_xor(h, off);
    }
    if ((tid & 63) == 0) { sv[tid >> 6] = v; sh2[tid >> 6] = h; }
    __syncthreads();
    if (tid == 0) {
        float sumv = sv[0] + sv[1] + sv[2] + sv[3];
        float sumh = sh2[0] + sh2[1] + sh2[2] + sh2[3];
        out[0] = sumv / (float)BB + 0.25f * sumh / ((float)BB * (float)CC);
    }
}

extern "C" void kernel_launch(void* const* d_in, const int* in_sizes, int n_in,
                              void* d_out, int out_size, void* d_ws, size_t ws_size,
                              hipStream_t stream) {
    const float* inputs  = (const float*)d_in[0];
    const int*   targets = (const int*)d_in[1];
    const float* lutc    = (const float*)d_in[2];
    const float* luti    = (const float*)d_in[3];
    float* out = (float*)d_out;
    float* ws  = (float*)d_ws;

    // ws layout (floats): maxp | sep | slp | hubp | vvals | wsA (128KB, ushort)
    const size_t statN = (size_t)2 * BB * NWG;   // 400128
    float* maxp  = ws;
    float* sep   = ws + statN;
    float* slp   = ws + 2 * statN;
    float* hubp  = ws + 3 * statN;
    float* vvals = hubp + NWG;
    unsigned short* wsA = (unsigned short*)(ws + 1202208);  // 16B-aligned, +128KB

    k_prep<<<16, 256, 0, stream>>>(inputs, wsA);
    k_main_mfma<<<NWG, 256, 0, stream>>>(wsA, lutc, luti, maxp, sep, slp, hubp);
    k_reduce<<<256, 256, 0, stream>>>(inputs, targets, lutc, luti, maxp, sep, slp, vvals);
    k_final<<<1, 256, 0, stream>>>(vvals, hubp, out);
}

// Round 9
// 324.568 us; speedup vs baseline: 1.1345x; 1.1345x over previous
//
#include <hip/hip_runtime.h>
#include <math.h>

// Problem constants (fixed by the reference)
#define BB 128          // batch
#define CC 100000       // classes
#define FF 256          // feature dim
#define NB 64           // classes per workgroup (4 waves x 16 cols)
#define NWG ((CC + NB - 1) / NB)   // 1563
#define SCALARF 20.0f
#define CHUNKB 32768    // LDS bytes per buffer: B 16KB + A 16KB

typedef __attribute__((ext_vector_type(8))) short short8;   // 8 bf16 = 4 VGPR (MFMA A/B frag)
typedef __attribute__((ext_vector_type(4))) float f32x4;    // MFMA C/D frag

// ---- fp32 -> bf16 split helpers (RNE via bit trick; deterministic) ----
__device__ __forceinline__ unsigned short bf16_rne(float f) {
    unsigned int u = __float_as_uint(f);
    u += 0x7FFFu + ((u >> 16) & 1u);
    return (unsigned short)(u >> 16);
}
__device__ __forceinline__ float bf16_to_f32(unsigned short h) {
    return __uint_as_float((unsigned int)h << 16);
}
__device__ __forceinline__ void split8(const float4& a, const float4& b,
                                       short8& hi, short8& lo) {
    float v[8] = {a.x, a.y, a.z, a.w, b.x, b.y, b.z, b.w};
#pragma unroll
    for (int j = 0; j < 8; ++j) {
        unsigned short h = bf16_rne(v[j]);
        hi[j] = (short)h;
        lo[j] = (short)bf16_rne(v[j] - bf16_to_f32(h));
    }
}

// ---------------------------------------------------------------------------
// K0: pre-split scaled inputs (x20) into MFMA A-fragment layout, hi/lo bf16.
// wsA[((kc*8+mt)*2+h)*512 + lane*8 + j]
//   = bf16_part_h( 20 * inputs[(lane&15)+16*mt][kc*32 + (lane>>4)*8 + j] )
// Contiguous 16KB per kc -> K1 DMA-stages one kc-chunk with linear src/dst.
// ---------------------------------------------------------------------------
__global__ __launch_bounds__(256) void k_prep(const float* __restrict__ inputs,
                                              unsigned short* __restrict__ wsA)
{
    int t    = blockIdx.x * 256 + threadIdx.x;   // 0..4095
    int lane = t & 63;
    int mt   = (t >> 6) & 7;
    int kc   = t >> 9;
    int row  = (lane & 15) + 16 * mt;
    int k0   = kc * 32 + ((lane >> 4) << 3);
    const float* src = inputs + (size_t)row * FF + k0;
    float4 x0 = *(const float4*)(src);
    float4 x1 = *(const float4*)(src + 4);
    float v[8] = {x0.x, x0.y, x0.z, x0.w, x1.x, x1.y, x1.z, x1.w};
    unsigned short h[8], l[8];
#pragma unroll
    for (int j = 0; j < 8; ++j) {
        float a = v[j] * SCALARF;
        h[j] = bf16_rne(a);
        l[j] = bf16_rne(a - bf16_to_f32(h[j]));
    }
    size_t base = (size_t)(kc * 8 + mt) * 2 * 512;   // frag = 512 ushorts = 1KB
    uint4 ph, pl;
    ph.x = (unsigned)h[0] | ((unsigned)h[1] << 16);
    ph.y = (unsigned)h[2] | ((unsigned)h[3] << 16);
    ph.z = (unsigned)h[4] | ((unsigned)h[5] << 16);
    ph.w = (unsigned)h[6] | ((unsigned)h[7] << 16);
    pl.x = (unsigned)l[0] | ((unsigned)l[1] << 16);
    pl.y = (unsigned)l[2] | ((unsigned)l[3] << 16);
    pl.z = (unsigned)l[4] | ((unsigned)l[5] << 16);
    pl.w = (unsigned)l[6] | ((unsigned)l[7] << 16);
    *(uint4*)(wsA + base + lane * 8)       = ph;
    *(uint4*)(wsA + base + 512 + lane * 8) = pl;
}

// ---------------------------------------------------------------------------
// Stage one K-chunk into LDS via async global_load_lds (vmcnt-only):
//   bytes [0,16384):     B both LUTs, 64 cols x 128B, source XOR-swizzled
//                        (rule #21 involution: linear dst / swz src / swz read)
//   bytes [16384,32768): A hi/lo frags for this kc, LINEAR copy of wsA chunk
// 8 DMA instructions per wave (4 B + 4 A).
// ---------------------------------------------------------------------------
__device__ __forceinline__ void stage_chunk(
    const float* __restrict__ lutc, const float* __restrict__ luti,
    const unsigned short* __restrict__ wsA,
    char* buf, int w, int lane, int cbase, int kc)
{
    const int dc = lane >> 3;      // col-within-group 0..7
    const int t  = lane & 7;       // 16B unit within 128B col-chunk
#pragma unroll
    for (int r = 0; r < 4; ++r) {
        const int s0   = 256 * r + 64 * w;       // wave-uniform slot base
        const int lut  = s0 >> 9;                // 0,0,1,1 across r
        const int c0   = (s0 >> 3) & 63;
        const int colb = c0 + dc;
        int srow = cbase + colb;
        srow = (srow < CC) ? srow : (CC - 1);    // clamp tail (masked later)
        const float* lp = lut ? luti : lutc;
        const char* src = (const char*)lp + (size_t)srow * 1024 + kc * 128
                          + ((t * 16) ^ ((colb & 7) << 4));
        char* dst = buf + s0 * 16;               // wave-uniform; +lane*16 implicit
        __builtin_amdgcn_global_load_lds(
            (const __attribute__((address_space(1))) unsigned int*)src,
            (__attribute__((address_space(3))) unsigned int*)dst,
            16, 0, 0);
    }
    // A chunk: wave w stages 4KB of the 16KB, purely linear
    const char* asrc = (const char*)wsA + (size_t)kc * 16384 + w * 4096 + lane * 16;
    char* adst = buf + 16384 + w * 4096;
#pragma unroll
    for (int r = 0; r < 4; ++r) {
        __builtin_amdgcn_global_load_lds(
            (const __attribute__((address_space(1))) unsigned int*)(asrc + r * 1024),
            (__attribute__((address_space(3))) unsigned int*)(adst + r * 1024),
            16, 0, 0);
    }
}

// ---------------------------------------------------------------------------
// K1: dual-GEMM via bf16-split MFMA (Ah*Bh + Al*Bh + Ah*Bl).
// BOTH operands flow through double-buffered LDS via DMA (vmcnt), consumed
// via batched ds_read_b128 (lgkmcnt). No per-MFMA global round-trips: the
// round-4/6 bottleneck (A-loads sunk per-mt + wsA evicted from L2 by the
// B-stream -> serialized ~800cy waits) is structurally removed. DMA for
// chunk k+1 is issued first each iteration and retires under the MFMAs.
// ---------------------------------------------------------------------------
__global__ __launch_bounds__(256, 2) void k_main_mfma(
    const unsigned short* __restrict__ wsA,
    const float* __restrict__ lutc,
    const float* __restrict__ luti,
    float* __restrict__ maxp,           // [2][128][NWG]
    float* __restrict__ sep,            // [2][128][NWG]
    float* __restrict__ slp,            // [2][128][NWG]
    float* __restrict__ hubp)           // [NWG]
{
    __shared__ __align__(16) char smemc[2 * CHUNKB];   // 64KB; epilogue aliases

    const int tid  = threadIdx.x;
    const int w    = tid >> 6;        // wave 0..3
    const int lane = tid & 63;
    const int cg   = lane & 15;       // col within wave's 16
    const int g    = lane >> 4;       // k-subgroup / D-row group
    const int wg   = blockIdx.x;
    const int cbase = wg * NB;
    const int colB = w * 16 + cg;     // col within block 0..63
    const int col  = cbase + colB;
    const bool valid = col < CC;
    const int sw   = (colB & 7) << 4; // read-side swizzle (matches source swizzle)

    f32x4 acc[2][8];
#pragma unroll
    for (int l2 = 0; l2 < 2; ++l2)
#pragma unroll
        for (int mt = 0; mt < 8; ++mt) acc[l2][mt] = (f32x4)(0.0f);

    // ---- prologue: stage chunk 0 into buf0 (barrier drains the DMA) ----
    stage_chunk(lutc, luti, wsA, smemc, w, lane, cbase, 0);
    __syncthreads();

#pragma unroll
    for (int kc = 0; kc < 8; ++kc) {
        char* bufC = smemc + (kc & 1) * CHUNKB;

        // 1. DMA-stage next chunk FIRST (retires under this iter's MFMAs;
        //    target buffer freed by the barrier that ended iter kc-1).
        if (kc < 7)
            stage_chunk(lutc, luti, wsA,
                        smemc + ((kc + 1) & 1) * CHUNKB, w, lane, cbase, kc + 1);

        // 2. B from LDS (swizzled read — returns linear global bytes)
        const char* bc = bufC + colB * 128;
        float4 c0v = *(const float4*)(bc + ((g * 32) ^ sw));
        float4 c1v = *(const float4*)(bc + ((g * 32 + 16) ^ sw));
        float4 i0v = *(const float4*)(bc + 8192 + ((g * 32) ^ sw));
        float4 i1v = *(const float4*)(bc + 8192 + ((g * 32 + 16) ^ sw));

        // 3. A-frags from LDS, batched (linear lane*16 — conflict-free)
        const char* ab = bufC + 16384 + lane * 16;
        short8 aF0[8], aF1[8];
#pragma unroll
        for (int mt = 0; mt < 8; ++mt) {
            aF0[mt] = *(const short8*)(ab + (mt * 2) * 1024);
            aF1[mt] = *(const short8*)(ab + (mt * 2 + 1) * 1024);
        }

        // 4. split B to hi/lo bf16
        short8 bhC, blC, bhI, blI;
        split8(c0v, c1v, bhC, blC);
        split8(i0v, i1v, bhI, blI);

        // 5. 48 MFMAs, acc0/acc1 interleaved (dep distance 2)
#pragma unroll
        for (int mt = 0; mt < 8; ++mt) {
            acc[0][mt] = __builtin_amdgcn_mfma_f32_16x16x32_bf16(aF0[mt], bhC, acc[0][mt], 0, 0, 0);
            acc[1][mt] = __builtin_amdgcn_mfma_f32_16x16x32_bf16(aF0[mt], bhI, acc[1][mt], 0, 0, 0);
            acc[0][mt] = __builtin_amdgcn_mfma_f32_16x16x32_bf16(aF1[mt], bhC, acc[0][mt], 0, 0, 0);
            acc[1][mt] = __builtin_amdgcn_mfma_f32_16x16x32_bf16(aF1[mt], bhI, acc[1][mt], 0, 0, 0);
            acc[0][mt] = __builtin_amdgcn_mfma_f32_16x16x32_bf16(aF0[mt], blC, acc[0][mt], 0, 0, 0);
            acc[1][mt] = __builtin_amdgcn_mfma_f32_16x16x32_bf16(aF0[mt], blI, acc[1][mt], 0, 0, 0);
        }
        // 6. barrier: drains this wave's DMA (issued ~1800cy earlier = free)
        //    and guards buffer reuse.
        __syncthreads();
    }

    // ---- epilogue (LDS buffers dead; alias reduction arrays) ----
    float* smem = (float*)smemc;
    float* sMax = smem;            // [2][4][128]
    float* sSe  = smem + 1024;
    float* sSl  = smem + 2048;
    float* hsh  = smem + 3072;     // [4]

    // D layout (m89-verified): col = lane&15 (class), row = 16*mt + 4*g + j (sample)

    // smooth-L1 partial (valid cols only)
    float hloc = 0.f;
#pragma unroll
    for (int mt = 0; mt < 8; ++mt)
#pragma unroll
        for (int j = 0; j < 4; ++j) {
            float d = fabsf(acc[0][mt][j] - acc[1][mt][j]);
            float hv = (d < 1.f) ? 0.5f * d * d : d - 0.5f;
            hloc += valid ? hv : 0.f;
        }

    // per-sample-row softmax partials over this wave's 16 cols
#pragma unroll
    for (int l2 = 0; l2 < 2; ++l2) {
#pragma unroll
        for (int mt = 0; mt < 8; ++mt) {
#pragma unroll
            for (int j = 0; j < 4; ++j) {
                float v  = acc[l2][mt][j];
                float mv = valid ? v : -3.0e38f;
                mv = fmaxf(mv, __shfl_xor(mv, 1));
                mv = fmaxf(mv, __shfl_xor(mv, 2));
                mv = fmaxf(mv, __shfl_xor(mv, 4));
                mv = fmaxf(mv, __shfl_xor(mv, 8));
                float e  = valid ? __expf(v - mv) : 0.f;
                float sl = valid ? v : 0.f;
                e  += __shfl_xor(e, 1);  e  += __shfl_xor(e, 2);
                e  += __shfl_xor(e, 4);  e  += __shfl_xor(e, 8);
                sl += __shfl_xor(sl, 1); sl += __shfl_xor(sl, 2);
                sl += __shfl_xor(sl, 4); sl += __shfl_xor(sl, 8);
                if (cg == 0) {
                    int r = 16 * mt + 4 * g + j;
                    sMax[(l2 * 4 + w) * 128 + r] = mv;
                    sSe [(l2 * 4 + w) * 128 + r] = e;
                    sSl [(l2 * 4 + w) * 128 + r] = sl;
                }
            }
        }
    }

    // huber wave reduce -> block
#pragma unroll
    for (int off = 1; off < 64; off <<= 1) hloc += __shfl_xor(hloc, off);
    if (lane == 0) hsh[w] = hloc;
    __syncthreads();

    // combine 4 waves per (lut,row) and write global partials
    {
        int l2 = tid >> 7, r = tid & 127;
        float m0 = sMax[(l2 * 4 + 0) * 128 + r], m1 = sMax[(l2 * 4 + 1) * 128 + r];
        float m2 = sMax[(l2 * 4 + 2) * 128 + r], m3 = sMax[(l2 * 4 + 3) * 128 + r];
        float m  = fmaxf(fmaxf(m0, m1), fmaxf(m2, m3));
        float se = sSe[(l2 * 4 + 0) * 128 + r] * __expf(m0 - m)
                 + sSe[(l2 * 4 + 1) * 128 + r] * __expf(m1 - m)
                 + sSe[(l2 * 4 + 2) * 128 + r] * __expf(m2 - m)
                 + sSe[(l2 * 4 + 3) * 128 + r] * __expf(m3 - m);
        float sl = sSl[(l2 * 4 + 0) * 128 + r] + sSl[(l2 * 4 + 1) * 128 + r]
                 + sSl[(l2 * 4 + 2) * 128 + r] + sSl[(l2 * 4 + 3) * 128 + r];
        size_t o = ((size_t)(l2 * BB + r)) * NWG + wg;
        maxp[o] = m; sep[o] = se; slp[o] = sl;
    }
    if (tid == 0) hubp[wg] = hsh[0] + hsh[1] + hsh[2] + hsh[3];
}

// ---------------------------------------------------------------------------
// K2: combine split-softmax partials per (lut, sample); target logit dot.
// Grid: 256 blocks (lut*128+b) x 256 threads.
// ---------------------------------------------------------------------------
__global__ __launch_bounds__(256) void k_reduce(
    const float* __restrict__ inputs, const int* __restrict__ targets,
    const float* __restrict__ lutc, const float* __restrict__ luti,
    const float* __restrict__ maxp, const float* __restrict__ sep,
    const float* __restrict__ slp, float* __restrict__ vvals)
{
    __shared__ float sM[4], sS[4], sSL[4], sDP;
    const int l    = blockIdx.x >> 7;
    const int b    = blockIdx.x & 127;
    const int tid  = threadIdx.x;
    const int wv   = tid >> 6;
    const int lane = tid & 63;
    const size_t base = ((size_t)(l * BB + b)) * NWG;

    float M = -3.0e38f, S = 0.f, SL = 0.f;
    for (int w = tid; w < NWG; w += 256) {
        float m = maxp[base + w];
        float s = sep[base + w];
        float nM = fmaxf(M, m);
        S = S * __expf(M - nM) + s * __expf(m - nM);
        M = nM;
        SL += slp[base + w];
    }
#pragma unroll
    for (int off = 1; off < 64; off <<= 1) {
        float m2 = __shfl_xor(M, off), s2 = __shfl_xor(S, off), sl2 = __shfl_xor(SL, off);
        float nM = fmaxf(M, m2);
        S = S * __expf(M - nM) + s2 * __expf(m2 - nM);
        M = nM;
        SL += sl2;
    }
    // target logit: wave 0 does the 256-feature fp32 dot
    if (wv == 0) {
        const int tgt = targets[b];
        const float* lut = (l == 0 ? lutc : luti) + (size_t)tgt * FF;
        const float* inp = inputs + (size_t)b * FF;
        float4 x = *(const float4*)(inp + lane * 4);
        float4 y = *(const float4*)(lut + lane * 4);
        float dp = x.x * y.x + x.y * y.y + x.z * y.z + x.w * y.w;
#pragma unroll
        for (int off = 1; off < 64; off <<= 1) dp += __shfl_xor(dp, off);
        if (lane == 0) sDP = dp;
    }
    if (lane == 0) { sM[wv] = M; sS[wv] = S; sSL[wv] = SL; }
    __syncthreads();
    if (tid == 0) {
        float m = fmaxf(fmaxf(sM[0], sM[1]), fmaxf(sM[2], sM[3]));
        float S4 = 0.f, SL4 = 0.f;
#pragma unroll
        for (int i = 0; i < 4; ++i) {
            S4  += sS[i] * __expf(sM[i] - m);
            SL4 += sSL[i];
        }
        float lt  = SCALARF * sDP;
        float lse = m + __logf(S4);
        vvals[blockIdx.x] = 0.9f * (lse - lt) + 0.1f * (lse - SL4 / (float)CC);
    }
}

// ---------------------------------------------------------------------------
// K3: final scalar reduction.
// ---------------------------------------------------------------------------
__global__ __launch_bounds__(256) void k_final(
    const float* __restrict__ vvals, const float* __restrict__ hubp,
    float* __restrict__ out)
{
    __shared__ float sv[4], sh2[4];
    const int tid = threadIdx.x;
    float v = vvals[tid];            // exactly 256 values
    float h = 0.f;
    for (int w = tid; w < NWG; w += 256) h += hubp[w];
#pragma unroll
    for (int off = 1; off < 64; off <<= 1) {
        v += __shfl_xor(v, off);
        h += __shfl_xor(h, off);
    }
    if ((tid & 63) == 0) { sv[tid >> 6] = v; sh2[tid >> 6] = h; }
    __syncthreads();
    if (tid == 0) {
        float sumv = sv[0] + sv[1] + sv[2] + sv[3];
        float sumh = sh2[0] + sh2[1] + sh2[2] + sh2[3];
        out[0] = sumv / (float)BB + 0.25f * sumh / ((float)BB * (float)CC);
    }
}

extern "C" void kernel_launch(void* const* d_in, const int* in_sizes, int n_in,
                              void* d_out, int out_size, void* d_ws, size_t ws_size,
                              hipStream_t stream) {
    const float* inputs  = (const float*)d_in[0];
    const int*   targets = (const int*)d_in[1];
    const float* lutc    = (const float*)d_in[2];
    const float* luti    = (const float*)d_in[3];
    float* out = (float*)d_out;
    float* ws  = (float*)d_ws;

    // ws layout (floats): maxp | sep | slp | hubp | vvals | wsA (128KB, ushort)
    const size_t statN = (size_t)2 * BB * NWG;   // 400128
    float* maxp  = ws;
    float* sep   = ws + statN;
    float* slp   = ws + 2 * statN;
    float* hubp  = ws + 3 * statN;
    float* vvals = hubp + NWG;
    unsigned short* wsA = (unsigned short*)(ws + 1202208);  // 16B-aligned, +128KB

    k_prep<<<16, 256, 0, stream>>>(inputs, wsA);
    k_main_mfma<<<NWG, 256, 0, stream>>>(wsA, lutc, luti, maxp, sep, slp, hubp);
    k_reduce<<<256, 256, 0, stream>>>(inputs, targets, lutc, luti, maxp, sep, slp, vvals);
    k_final<<<1, 256, 0, stream>>>(vvals, hubp, out);
}

// Round 11
// 317.846 us; speedup vs baseline: 1.1585x; 1.0211x over previous
//
#include <hip/hip_runtime.h>
#include <math.h>

// Problem constants (fixed by the reference)
#define BB 128          // batch
#define CC 100000       // classes
#define FF 256          // feature dim
#define NB 64           // classes per workgroup (4 waves x 16 cols)
#define NWG ((CC + NB - 1) / NB)   // 1563
#define SCALARF 20.0f
#define CHUNKB 32768    // LDS bytes per buffer: B 16KB + A 16KB

typedef __attribute__((ext_vector_type(8))) short short8;   // 8 bf16 = 4 VGPR (MFMA A/B frag)
typedef __attribute__((ext_vector_type(4))) float f32x4;    // MFMA C/D frag

// ---- fp32 -> bf16 split helpers (RNE via bit trick; deterministic) ----
__device__ __forceinline__ unsigned short bf16_rne(float f) {
    unsigned int u = __float_as_uint(f);
    u += 0x7FFFu + ((u >> 16) & 1u);
    return (unsigned short)(u >> 16);
}
__device__ __forceinline__ float bf16_to_f32(unsigned short h) {
    return __uint_as_float((unsigned int)h << 16);
}
__device__ __forceinline__ void split8(const float4& a, const float4& b,
                                       short8& hi, short8& lo) {
    float v[8] = {a.x, a.y, a.z, a.w, b.x, b.y, b.z, b.w};
#pragma unroll
    for (int j = 0; j < 8; ++j) {
        unsigned short h = bf16_rne(v[j]);
        hi[j] = (short)h;
        lo[j] = (short)bf16_rne(v[j] - bf16_to_f32(h));
    }
}

// ---------------------------------------------------------------------------
// K0: pre-split scaled inputs (x20) into MFMA A-fragment layout, hi/lo bf16.
// wsA[((kc*8+mt)*2+h)*512 + lane*8 + j]
//   = bf16_part_h( 20 * inputs[(lane&15)+16*mt][kc*32 + (lane>>4)*8 + j] )
// Contiguous 16KB per kc -> K1 DMA-stages one kc-chunk with linear src/dst.
// ---------------------------------------------------------------------------
__global__ __launch_bounds__(256) void k_prep(const float* __restrict__ inputs,
                                              unsigned short* __restrict__ wsA)
{
    int t    = blockIdx.x * 256 + threadIdx.x;   // 0..4095
    int lane = t & 63;
    int mt   = (t >> 6) & 7;
    int kc   = t >> 9;
    int row  = (lane & 15) + 16 * mt;
    int k0   = kc * 32 + ((lane >> 4) << 3);
    const float* src = inputs + (size_t)row * FF + k0;
    float4 x0 = *(const float4*)(src);
    float4 x1 = *(const float4*)(src + 4);
    float v[8] = {x0.x, x0.y, x0.z, x0.w, x1.x, x1.y, x1.z, x1.w};
    unsigned short h[8], l[8];
#pragma unroll
    for (int j = 0; j < 8; ++j) {
        float a = v[j] * SCALARF;
        h[j] = bf16_rne(a);
        l[j] = bf16_rne(a - bf16_to_f32(h[j]));
    }
    size_t base = (size_t)(kc * 8 + mt) * 2 * 512;   // frag = 512 ushorts = 1KB
    uint4 ph, pl;
    ph.x = (unsigned)h[0] | ((unsigned)h[1] << 16);
    ph.y = (unsigned)h[2] | ((unsigned)h[3] << 16);
    ph.z = (unsigned)h[4] | ((unsigned)h[5] << 16);
    ph.w = (unsigned)h[6] | ((unsigned)h[7] << 16);
    pl.x = (unsigned)l[0] | ((unsigned)l[1] << 16);
    pl.y = (unsigned)l[2] | ((unsigned)l[3] << 16);
    pl.z = (unsigned)l[4] | ((unsigned)l[5] << 16);
    pl.w = (unsigned)l[6] | ((unsigned)l[7] << 16);
    *(uint4*)(wsA + base + lane * 8)       = ph;
    *(uint4*)(wsA + base + 512 + lane * 8) = pl;
}

// ---------------------------------------------------------------------------
// Stage one K-chunk into LDS via async global_load_lds (vmcnt-only, 8/wave):
//   bytes [0,16384):     B both LUTs, 64 cols x 128B, source XOR-swizzled
//                        (rule #21 involution: linear dst / swz src / swz read)
//   bytes [16384,32768): A hi/lo frags for this kc, LINEAR copy of wsA chunk
// ---------------------------------------------------------------------------
__device__ __forceinline__ void stage_chunk(
    const float* __restrict__ lutc, const float* __restrict__ luti,
    const unsigned short* __restrict__ wsA,
    char* buf, int w, int lane, int cbase, int kc)
{
    const int dc = lane >> 3;      // col-within-group 0..7
    const int t  = lane & 7;       // 16B unit within 128B col-chunk
#pragma unroll
    for (int r = 0; r < 4; ++r) {
        const int s0   = 256 * r + 64 * w;       // wave-uniform slot base
        const int lut  = s0 >> 9;                // 0,0,1,1 across r
        const int c0   = (s0 >> 3) & 63;
        const int colb = c0 + dc;
        int srow = cbase + colb;
        srow = (srow < CC) ? srow : (CC - 1);    // clamp tail (masked later)
        const float* lp = lut ? luti : lutc;
        const char* src = (const char*)lp + (size_t)srow * 1024 + kc * 128
                          + ((t * 16) ^ ((colb & 7) << 4));
        char* dst = buf + s0 * 16;               // wave-uniform; +lane*16 implicit
        __builtin_amdgcn_global_load_lds(
            (const __attribute__((address_space(1))) unsigned int*)src,
            (__attribute__((address_space(3))) unsigned int*)dst,
            16, 0, 0);
    }
    // A chunk: wave w stages 4KB of the 16KB, purely linear
    const char* asrc = (const char*)wsA + (size_t)kc * 16384 + w * 4096 + lane * 16;
    char* adst = buf + 16384 + w * 4096;
#pragma unroll
    for (int r = 0; r < 4; ++r) {
        __builtin_amdgcn_global_load_lds(
            (const __attribute__((address_space(1))) unsigned int*)(asrc + r * 1024),
            (__attribute__((address_space(3))) unsigned int*)(adst + r * 1024),
            16, 0, 0);
    }
}

// ---------------------------------------------------------------------------
// K1: dual-GEMM via bf16-split MFMA (Ah*Bh + Al*Bh + Ah*Bl).
// T4 structure: counted vmcnt + RAW s_barrier, prefetch distance 2.
// Round-9 diagnosis: __syncthreads()'s implicit vmcnt(0) drained the DMA
// queue every iteration -> burst-and-drain, ~13K cy/iter vs ~600 compute.
// Now per-wave vmcnt stays >=8 in flight through the whole loop:
//   top:  vmcnt(8) [chunk kc retired, kc+1 flying] ; barrier (publish)
//   mid:  lgkmcnt(0) ; barrier (all reads of bufC done)
//   then: stage chunk kc+2 into bufC's space ; split ; 48 MFMA
// Each wave's counted wait covers its own 8 DMAs; barrier-after-wait
// publishes all 32 (HK pattern). sched_barrier(0) per rule #18.
// ---------------------------------------------------------------------------
__global__ __launch_bounds__(256, 2) void k_main_mfma(
    const unsigned short* __restrict__ wsA,
    const float* __restrict__ lutc,
    const float* __restrict__ luti,
    float* __restrict__ maxp,           // [2][128][NWG]
    float* __restrict__ sep,            // [2][128][NWG]
    float* __restrict__ slp,            // [2][128][NWG]
    float* __restrict__ hubp)           // [NWG]
{
    __shared__ __align__(16) char smemc[2 * CHUNKB];   // 64KB; epilogue aliases

    const int tid  = threadIdx.x;
    const int w    = tid >> 6;        // wave 0..3
    const int lane = tid & 63;
    const int cg   = lane & 15;       // col within wave's 16
    const int g    = lane >> 4;       // k-subgroup / D-row group
    const int wg   = blockIdx.x;
    const int cbase = wg * NB;
    const int colB = w * 16 + cg;     // col within block 0..63
    const int col  = cbase + colB;
    const bool valid = col < CC;
    const int sw   = (colB & 7) << 4; // read-side swizzle (matches source swizzle)

    f32x4 acc[2][8];
#pragma unroll
    for (int l2 = 0; l2 < 2; ++l2)
#pragma unroll
        for (int mt = 0; mt < 8; ++mt) acc[l2][mt] = (f32x4)(0.0f);

    // ---- prologue: stage chunks 0 and 1 (16 DMAs in flight, no drain) ----
    stage_chunk(lutc, luti, wsA, smemc, w, lane, cbase, 0);
    stage_chunk(lutc, luti, wsA, smemc + CHUNKB, w, lane, cbase, 1);

#pragma unroll
    for (int kc = 0; kc < 8; ++kc) {
        char* bufC = smemc + (kc & 1) * CHUNKB;

        // 1. counted wait: my 8 chunk-kc DMAs are the oldest outstanding.
        if (kc == 7) { asm volatile("s_waitcnt vmcnt(0)" ::: "memory"); }
        else         { asm volatile("s_waitcnt vmcnt(8)" ::: "memory"); }
        __builtin_amdgcn_sched_barrier(0);
        __builtin_amdgcn_s_barrier();   // all waves' chunk-kc writes visible

        // 2. B from LDS (swizzled read — returns linear global bytes)
        const char* bc = bufC + colB * 128;
        float4 c0v = *(const float4*)(bc + ((g * 32) ^ sw));
        float4 c1v = *(const float4*)(bc + ((g * 32 + 16) ^ sw));
        float4 i0v = *(const float4*)(bc + 8192 + ((g * 32) ^ sw));
        float4 i1v = *(const float4*)(bc + 8192 + ((g * 32 + 16) ^ sw));

        //    A-frags from LDS, batched (linear lane*16 — conflict-free)
        const char* ab = bufC + 16384 + lane * 16;
        short8 aF0[8], aF1[8];
#pragma unroll
        for (int mt = 0; mt < 8; ++mt) {
            aF0[mt] = *(const short8*)(ab + (mt * 2) * 1024);
            aF1[mt] = *(const short8*)(ab + (mt * 2 + 1) * 1024);
        }

        // 3. all MY reads of bufC retired; publish across waves.
        asm volatile("s_waitcnt lgkmcnt(0)" ::: "memory");
        __builtin_amdgcn_sched_barrier(0);
        __builtin_amdgcn_s_barrier();   // all waves done reading bufC

        // 4. stage chunk kc+2 into bufC's space (write-after-read safe now);
        //    issues sit in the queue under the MFMAs below, waited at kc+2.
        if (kc < 6)
            stage_chunk(lutc, luti, wsA, bufC, w, lane, cbase, kc + 2);

        // 5. split B to hi/lo bf16 (VALU, overlaps DMA issue)
        short8 bhC, blC, bhI, blI;
        split8(c0v, c1v, bhC, blC);
        split8(i0v, i1v, bhI, blI);

        // 6. 48 MFMAs, acc0/acc1 interleaved (dep distance 2)
#pragma unroll
        for (int mt = 0; mt < 8; ++mt) {
            acc[0][mt] = __builtin_amdgcn_mfma_f32_16x16x32_bf16(aF0[mt], bhC, acc[0][mt], 0, 0, 0);
            acc[1][mt] = __builtin_amdgcn_mfma_f32_16x16x32_bf16(aF0[mt], bhI, acc[1][mt], 0, 0, 0);
            acc[0][mt] = __builtin_amdgcn_mfma_f32_16x16x32_bf16(aF1[mt], bhC, acc[0][mt], 0, 0, 0);
            acc[1][mt] = __builtin_amdgcn_mfma_f32_16x16x32_bf16(aF1[mt], bhI, acc[1][mt], 0, 0, 0);
            acc[0][mt] = __builtin_amdgcn_mfma_f32_16x16x32_bf16(aF0[mt], blC, acc[0][mt], 0, 0, 0);
            acc[1][mt] = __builtin_amdgcn_mfma_f32_16x16x32_bf16(aF0[mt], blI, acc[1][mt], 0, 0, 0);
        }
    }

    // ---- epilogue (LDS buffers dead: no DMA pending, all reads retired) ----
    __syncthreads();               // full drain before aliasing the buffers
    float* smem = (float*)smemc;
    float* sMax = smem;            // [2][4][128]
    float* sSe  = smem + 1024;
    float* sSl  = smem + 2048;
    float* hsh  = smem + 3072;     // [4]

    // D layout (m89-verified): col = lane&15 (class), row = 16*mt + 4*g + j (sample)

    // smooth-L1 partial (valid cols only)
    float hloc = 0.f;
#pragma unroll
    for (int mt = 0; mt < 8; ++mt)
#pragma unroll
        for (int j = 0; j < 4; ++j) {
            float d = fabsf(acc[0][mt][j] - acc[1][mt][j]);
            float hv = (d < 1.f) ? 0.5f * d * d : d - 0.5f;
            hloc += valid ? hv : 0.f;
        }

    // per-sample-row softmax partials over this wave's 16 cols
#pragma unroll
    for (int l2 = 0; l2 < 2; ++l2) {
#pragma unroll
        for (int mt = 0; mt < 8; ++mt) {
#pragma unroll
            for (int j = 0; j < 4; ++j) {
                float v  = acc[l2][mt][j];
                float mv = valid ? v : -3.0e38f;
                mv = fmaxf(mv, __shfl_xor(mv, 1));
                mv = fmaxf(mv, __shfl_xor(mv, 2));
                mv = fmaxf(mv, __shfl_xor(mv, 4));
                mv = fmaxf(mv, __shfl_xor(mv, 8));
                float e  = valid ? __expf(v - mv) : 0.f;
                float sl = valid ? v : 0.f;
                e  += __shfl_xor(e, 1);  e  += __shfl_xor(e, 2);
                e  += __shfl_xor(e, 4);  e  += __shfl_xor(e, 8);
                sl += __shfl_xor(sl, 1); sl += __shfl_xor(sl, 2);
                sl += __shfl_xor(sl, 4); sl += __shfl_xor(sl, 8);
                if (cg == 0) {
                    int r = 16 * mt + 4 * g + j;
                    sMax[(l2 * 4 + w) * 128 + r] = mv;
                    sSe [(l2 * 4 + w) * 128 + r] = e;
                    sSl [(l2 * 4 + w) * 128 + r] = sl;
                }
            }
        }
    }

    // huber wave reduce -> block
#pragma unroll
    for (int off = 1; off < 64; off <<= 1) hloc += __shfl_xor(hloc, off);
    if (lane == 0) hsh[w] = hloc;
    __syncthreads();

    // combine 4 waves per (lut,row) and write global partials
    {
        int l2 = tid >> 7, r = tid & 127;
        float m0 = sMax[(l2 * 4 + 0) * 128 + r], m1 = sMax[(l2 * 4 + 1) * 128 + r];
        float m2 = sMax[(l2 * 4 + 2) * 128 + r], m3 = sMax[(l2 * 4 + 3) * 128 + r];
        float m  = fmaxf(fmaxf(m0, m1), fmaxf(m2, m3));
        float se = sSe[(l2 * 4 + 0) * 128 + r] * __expf(m0 - m)
                 + sSe[(l2 * 4 + 1) * 128 + r] * __expf(m1 - m)
                 + sSe[(l2 * 4 + 2) * 128 + r] * __expf(m2 - m)
                 + sSe[(l2 * 4 + 3) * 128 + r] * __expf(m3 - m);
        float sl = sSl[(l2 * 4 + 0) * 128 + r] + sSl[(l2 * 4 + 1) * 128 + r]
                 + sSl[(l2 * 4 + 2) * 128 + r] + sSl[(l2 * 4 + 3) * 128 + r];
        size_t o = ((size_t)(l2 * BB + r)) * NWG + wg;
        maxp[o] = m; sep[o] = se; slp[o] = sl;
    }
    if (tid == 0) hubp[wg] = hsh[0] + hsh[1] + hsh[2] + hsh[3];
}

// ---------------------------------------------------------------------------
// K2: combine split-softmax partials per (lut, sample); target logit dot.
// Grid: 256 blocks (lut*128+b) x 256 threads.
// ---------------------------------------------------------------------------
__global__ __launch_bounds__(256) void k_reduce(
    const float* __restrict__ inputs, const int* __restrict__ targets,
    const float* __restrict__ lutc, const float* __restrict__ luti,
    const float* __restrict__ maxp, const float* __restrict__ sep,
    const float* __restrict__ slp, float* __restrict__ vvals)
{
    __shared__ float sM[4], sS[4], sSL[4], sDP;
    const int l    = blockIdx.x >> 7;
    const int b    = blockIdx.x & 127;
    const int tid  = threadIdx.x;
    const int wv   = tid >> 6;
    const int lane = tid & 63;
    const size_t base = ((size_t)(l * BB + b)) * NWG;

    float M = -3.0e38f, S = 0.f, SL = 0.f;
    for (int w = tid; w < NWG; w += 256) {
        float m = maxp[base + w];
        float s = sep[base + w];
        float nM = fmaxf(M, m);
        S = S * __expf(M - nM) + s * __expf(m - nM);
        M = nM;
        SL += slp[base + w];
    }
#pragma unroll
    for (int off = 1; off < 64; off <<= 1) {
        float m2 = __shfl_xor(M, off), s2 = __shfl_xor(S, off), sl2 = __shfl_xor(SL, off);
        float nM = fmaxf(M, m2);
        S = S * __expf(M - nM) + s2 * __expf(m2 - nM);
        M = nM;
        SL += sl2;
    }
    // target logit: wave 0 does the 256-feature fp32 dot
    if (wv == 0) {
        const int tgt = targets[b];
        const float* lut = (l == 0 ? lutc : luti) + (size_t)tgt * FF;
        const float* inp = inputs + (size_t)b * FF;
        float4 x = *(const float4*)(inp + lane * 4);
        float4 y = *(const float4*)(lut + lane * 4);
        float dp = x.x * y.x + x.y * y.y + x.z * y.z + x.w * y.w;
#pragma unroll
        for (int off = 1; off < 64; off <<= 1) dp += __shfl_xor(dp, off);
        if (lane == 0) sDP = dp;
    }
    if (lane == 0) { sM[wv] = M; sS[wv] = S; sSL[wv] = SL; }
    __syncthreads();
    if (tid == 0) {
        float m = fmaxf(fmaxf(sM[0], sM[1]), fmaxf(sM[2], sM[3]));
        float S4 = 0.f, SL4 = 0.f;
#pragma unroll
        for (int i = 0; i < 4; ++i) {
            S4  += sS[i] * __expf(sM[i] - m);
            SL4 += sSL[i];
        }
        float lt  = SCALARF * sDP;
        float lse = m + __logf(S4);
        vvals[blockIdx.x] = 0.9f * (lse - lt) + 0.1f * (lse - SL4 / (float)CC);
    }
}

// ---------------------------------------------------------------------------
// K3: final scalar reduction.
// ---------------------------------------------------------------------------
__global__ __launch_bounds__(256) void k_final(
    const float* __restrict__ vvals, const float* __restrict__ hubp,
    float* __restrict__ out)
{
    __shared__ float sv[4], sh2[4];
    const int tid = threadIdx.x;
    float v = vvals[tid];            // exactly 256 values
    float h = 0.f;
    for (int w = tid; w < NWG; w += 256) h += hubp[w];
#pragma unroll
    for (int off = 1; off < 64; off <<= 1) {
        v += __shfl_xor(v, off);
        h += __shfl_xor(h, off);
    }
    if ((tid & 63) == 0) { sv[tid >> 6] = v; sh2[tid >> 6] = h; }
    __syncthreads();
    if (tid == 0) {
        float sumv = sv[0] + sv[1] + sv[2] + sv[3];
        float sumh = sh2[0] + sh2[1] + sh2[2] + sh2[3];
        out[0] = sumv / (float)BB + 0.25f * sumh / ((float)BB * (float)CC);
    }
}

extern "C" void kernel_launch(void* const* d_in, const int* in_sizes, int n_in,
                              void* d_out, int out_size, void* d_ws, size_t ws_size,
                              hipStream_t stream) {
    const float* inputs  = (const float*)d_in[0];
    const int*   targets = (const int*)d_in[1];
    const float* lutc    = (const float*)d_in[2];
    const float* luti    = (const float*)d_in[3];
    float* out = (float*)d_out;
    float* ws  = (float*)d_ws;

    // ws layout (floats): maxp | sep | slp | hubp | vvals | wsA (128KB, ushort)
    const size_t statN = (size_t)2 * BB * NWG;   // 400128
    float* maxp  = ws;
    float* sep   = ws + statN;
    float* slp   = ws + 2 * statN;
    float* hubp  = ws + 3 * statN;
    float* vvals = hubp + NWG;
    unsigned short* wsA = (unsigned short*)(ws + 1202208);  // 16B-aligned, +128KB

    k_prep<<<16, 256, 0, stream>>>(inputs, wsA);
    k_main_mfma<<<NWG, 256, 0, stream>>>(wsA, lutc, luti, maxp, sep, slp, hubp);
    k_reduce<<<256, 256, 0, stream>>>(inputs, targets, lutc, luti, maxp, sep, slp, vvals);
    k_final<<<1, 256, 0, stream>>>(vvals, hubp, out);
}